// Round 7
// baseline (561.701 us; speedup 1.0000x reference)
//
#include <hip/hip_runtime.h>
#include <hip/hip_fp16.h>

#define C 128
#define NOUT 2
#define ALPHA 0.1f
#define SLOPE 0.01f
#define ZP 136   // padded LDS row stride in halves (272 B, 16B-aligned)

typedef _Float16 half4v __attribute__((ext_vector_type(4)));
typedef float float4v __attribute__((ext_vector_type(4)));

// ---------------- graph preprocessing ----------------

__global__ void count_kernel(const int* __restrict__ col, int* __restrict__ cnt, int E) {
    int e = blockIdx.x * 256 + threadIdx.x;
    if (e < E) atomicAdd(&cnt[col[e]], 1);
}

// per-1024-chunk exclusive scan + chunk totals; also computes dinv
__global__ __launch_bounds__(1024) void scanA_kernel(const int* __restrict__ cnt,
                                                     int* __restrict__ offs,
                                                     int* __restrict__ bsum,
                                                     float* __restrict__ dinv, int n) {
    __shared__ int wsum[16];
    int t = threadIdx.x, lane = t & 63, wv = t >> 6;
    int i = blockIdx.x * 1024 + t;
    int v = (i < n) ? cnt[i] : 0;
    if (i < n) dinv[i] = rsqrtf((float)(v + 1));   // +1 self-loop
    int sc = v;
    #pragma unroll
    for (int d = 1; d < 64; d <<= 1) {
        int u = __shfl_up(sc, d);
        if (lane >= d) sc += u;
    }
    if (lane == 63) wsum[wv] = sc;
    __syncthreads();
    int woff = 0;
    #pragma unroll
    for (int j = 0; j < 16; ++j) woff += (j < wv) ? wsum[j] : 0;
    if (i < n) offs[i] = woff + sc - v;            // block-local exclusive
    if (t == 0) {
        int tot = 0;
        #pragma unroll
        for (int j = 0; j < 16; ++j) tot += wsum[j];
        bsum[blockIdx.x] = tot;
    }
}

__global__ __launch_bounds__(1024) void scanB_kernel(const int* __restrict__ bsum,
                                                     int* __restrict__ bbase, int nb) {
    __shared__ int wsum[16];
    int t = threadIdx.x, lane = t & 63, wv = t >> 6;
    int v = (t < nb) ? bsum[t] : 0;
    int sc = v;
    #pragma unroll
    for (int d = 1; d < 64; d <<= 1) {
        int u = __shfl_up(sc, d);
        if (lane >= d) sc += u;
    }
    if (lane == 63) wsum[wv] = sc;
    __syncthreads();
    int woff = 0;
    #pragma unroll
    for (int j = 0; j < 16; ++j) woff += (j < wv) ? wsum[j] : 0;
    if (t < nb) bbase[t] = woff + sc - v;
}

__global__ void scanC_kernel(int* __restrict__ offs, int* __restrict__ cursor,
                             const int* __restrict__ bbase, int n, int E) {
    int i = blockIdx.x * 256 + threadIdx.x;
    if (i < n) {
        int o = offs[i] + bbase[i >> 10];
        offs[i] = o;
        cursor[i] = o;
    }
    if (i == n) offs[n] = E;
}

// packed edge metadata: {src, float-bits of norm}
__global__ void fill_kernel(const int* __restrict__ row, const int* __restrict__ col,
                            const float* __restrict__ dinv, int* __restrict__ cursor,
                            int2* __restrict__ csr, int E) {
    int e = blockIdx.x * 256 + threadIdx.x;
    if (e >= E) return;
    int r = row[e], c = col[e];
    int pos = atomicAdd(&cursor[c], 1);
    int2 m;
    m.x = r;
    m.y = __float_as_int(dinv[r] * dinv[c]);
    csr[pos] = m;
}

// fp32 node-major -> fp16 node-major
__global__ __launch_bounds__(256) void convert_kernel(const float* __restrict__ x,
                                                      __half* __restrict__ xh, int n) {
    int g = blockIdx.x * 256 + threadIdx.x;
    if (g >= n * 32) return;
    float4 v = ((const float4*)x)[g];
    union { __half2 h; unsigned u; } a, b;
    a.h = __float22half2_rn(make_float2(v.x, v.y));
    b.h = __float22half2_rn(make_float2(v.z, v.w));
    ((uint2*)xh)[g] = make_uint2(a.u, b.u);
}

// conv weights: fp32 [l][k][n] -> fp16 [l][n][k]
__global__ void wtc_kernel(const float* __restrict__ W, _Float16* __restrict__ WT, int total) {
    int idx = blockIdx.x * 256 + threadIdx.x;
    if (idx >= total) return;
    int l = idx >> 14, rem = idx & 16383;
    int nrow = rem >> 7, kk = rem & 127;
    WT[idx] = (_Float16)W[(l << 14) + kk * C + nrow];
}

// dense weights: fp32 [k][256] -> fp16 [256][k]
__global__ void wdc_kernel(const float* __restrict__ wd, _Float16* __restrict__ WDT) {
    int idx = blockIdx.x * 256 + threadIdx.x;
    if (idx >= 256 * C) return;
    int nrow = idx >> 7, kk = idx & 127;
    WDT[idx] = (_Float16)wd[kk * 256 + nrow];
}

__device__ __forceinline__ void accum8(float* a, uint4 q, float w) {
    union { unsigned u; __half2 h; } c;
    float2 f;
    c.u = q.x; f = __half22float2(c.h); a[0] += w * f.x; a[1] += w * f.y;
    c.u = q.y; f = __half22float2(c.h); a[2] += w * f.x; a[3] += w * f.y;
    c.u = q.z; f = __half22float2(c.h); a[4] += w * f.x; a[5] += w * f.y;
    c.u = q.w; f = __half22float2(c.h); a[6] += w * f.x; a[7] += w * f.y;
}

__device__ __forceinline__ uint4 pack8(const float* a) {
    union { __half2 h; unsigned u; } c0, c1, c2, c3;
    c0.h = __float22half2_rn(make_float2(a[0], a[1]));
    c1.h = __float22half2_rn(make_float2(a[2], a[3]));
    c2.h = __float22half2_rn(make_float2(a[4], a[5]));
    c3.h = __float22half2_rn(make_float2(a[6], a[7]));
    return make_uint4(c0.u, c1.u, c2.u, c3.u);
}

// ---------------- aggregation: one wave per node; eslot(0..3) x cg(0..15) uint4 lanes;
// unroll-4 -> 16 x 16B gathers in flight per wave
__global__ __launch_bounds__(256) void agg_kernel(
    const __half* __restrict__ xc, const int* __restrict__ offs,
    const int2* __restrict__ csr, const float* __restrict__ dinv,
    __half* __restrict__ h, int n)
{
    int node = blockIdx.x * 4 + (threadIdx.x >> 6);
    if (node >= n) return;
    int lane = threadIdx.x & 63;
    int eslot = lane >> 4, cg = lane & 15;
    const uint4* x4 = (const uint4*)xc;
    float a0[8] = {}, a1[8] = {}, a2[8] = {}, a3[8] = {};
    int beg = offs[node], end = offs[node + 1];
    int k = beg + eslot;
    for (; k + 12 < end; k += 16) {
        int2 m0 = csr[k], m1 = csr[k + 4], m2 = csr[k + 8], m3 = csr[k + 12];
        uint4 q0 = x4[(size_t)m0.x * 16 + cg];
        uint4 q1 = x4[(size_t)m1.x * 16 + cg];
        uint4 q2 = x4[(size_t)m2.x * 16 + cg];
        uint4 q3 = x4[(size_t)m3.x * 16 + cg];
        accum8(a0, q0, __int_as_float(m0.y));
        accum8(a1, q1, __int_as_float(m1.y));
        accum8(a2, q2, __int_as_float(m2.y));
        accum8(a3, q3, __int_as_float(m3.y));
    }
    for (; k < end; k += 4) {
        int2 m = csr[k];
        uint4 q = x4[(size_t)m.x * 16 + cg];
        accum8(a0, q, __int_as_float(m.y));
    }
    #pragma unroll
    for (int j = 0; j < 8; ++j) a0[j] += a1[j] + a2[j] + a3[j];
    #pragma unroll
    for (int j = 0; j < 8; ++j) {
        a0[j] += __shfl_xor(a0[j], 16);
        a0[j] += __shfl_xor(a0[j], 32);
    }
    if (eslot == 0) {
        float di = dinv[node], sw = di * di;
        uint4 qs = x4[(size_t)node * 16 + cg];
        accum8(a0, qs, sw);
        ((uint4*)h)[(size_t)node * 16 + cg] = pack8(a0);
    }
}

// ---------------- layer GEMM (MFMA): xn = leaky(((1-a)h + a*x0) @ W) ; in-place ok
// 64 nodes/block, 4 waves x 16 nodes x 128 cols; WT fp16 [n][k] read from global (L1/L2-hot)
__global__ __launch_bounds__(256) void layer_mfma(
    const __half* __restrict__ hbuf, const __half* __restrict__ x0h,
    const _Float16* __restrict__ WT, __half* __restrict__ xn, int n)
{
    __shared__ _Float16 zl[64 * ZP];
    int i0 = blockIdx.x * 64;
    int t = threadIdx.x;
    const half4v* h4 = (const half4v*)hbuf;
    const half4v* x4 = (const half4v*)x0h;
    for (int p = t; p < 64 * 32; p += 256) {       // 32 half4 per row
        int r = p >> 5, c4 = p & 31;
        half4v zv;
        if (i0 + r < n) {
            half4v hv = h4[(size_t)(i0 + r) * 32 + c4];
            half4v xv = x4[(size_t)(i0 + r) * 32 + c4];
            #pragma unroll
            for (int j = 0; j < 4; ++j)
                zv[j] = (_Float16)((1.f - ALPHA) * (float)hv[j] + ALPHA * (float)xv[j]);
        } else {
            #pragma unroll
            for (int j = 0; j < 4; ++j) zv[j] = (_Float16)0.f;
        }
        *(half4v*)&zl[r * ZP + c4 * 4] = zv;
    }
    __syncthreads();

    int w = t >> 6, lane = t & 63;
    int c = lane & 15, g = lane >> 4;
    float4v acc[8];
    #pragma unroll
    for (int i = 0; i < 8; ++i) acc[i] = (float4v)0.f;
    const _Float16* arow = &zl[(w * 16 + c) * ZP];
    #pragma unroll
    for (int kb = 0; kb < 8; ++kb) {
        half4v af = *(const half4v*)&arow[kb * 16 + 4 * g];
        #pragma unroll
        for (int nt = 0; nt < 8; ++nt) {
            half4v bf = *(const half4v*)&WT[(nt * 16 + c) * C + kb * 16 + 4 * g];
            acc[nt] = __builtin_amdgcn_mfma_f32_16x16x16f16(af, bf, acc[nt], 0, 0, 0);
        }
    }
    __syncthreads();   // all waves done reading zl
    #pragma unroll
    for (int nt = 0; nt < 8; ++nt) {
        #pragma unroll
        for (int r = 0; r < 4; ++r) {
            float v = acc[nt][r];
            v = v > 0.f ? v : SLOPE * v;
            zl[(w * 16 + 4 * g + r) * ZP + nt * 16 + c] = (_Float16)v;
        }
    }
    __syncthreads();
    for (int p = t; p < 64 * 16; p += 256) {       // 16 uint4 (8 halves) per row
        int r = p >> 4, c8 = p & 15;
        int node = i0 + r;
        if (node < n)
            ((uint4*)xn)[(size_t)node * 16 + c8] = *(uint4*)&zl[r * ZP + c8 * 8];
    }
}

// ---------------- dense head (MFMA): out = (x@wd + bd) @ wo + bo
__global__ __launch_bounds__(256) void dense_mfma(
    const __half* __restrict__ xin, const _Float16* __restrict__ WDT,
    const float* __restrict__ bd, const float* __restrict__ wo,
    const float* __restrict__ bo, float* __restrict__ out, int n)
{
    __shared__ _Float16 xl[64 * ZP];
    int i0 = blockIdx.x * 64;
    int t = threadIdx.x;
    const uint4* g4 = (const uint4*)xin;
    for (int p = t; p < 64 * 16; p += 256) {
        int r = p >> 4, c8 = p & 15;
        uint4 v = make_uint4(0, 0, 0, 0);
        if (i0 + r < n) v = g4[(size_t)(i0 + r) * 16 + c8];
        *(uint4*)&xl[r * ZP + c8 * 8] = v;
    }
    __syncthreads();

    int w = t >> 6, lane = t & 63;
    int c = lane & 15, g = lane >> 4;
    float4v acc[16];
    #pragma unroll
    for (int i = 0; i < 16; ++i) acc[i] = (float4v)0.f;
    const _Float16* arow = &xl[(w * 16 + c) * ZP];
    #pragma unroll
    for (int kb = 0; kb < 8; ++kb) {
        half4v af = *(const half4v*)&arow[kb * 16 + 4 * g];
        #pragma unroll
        for (int nt = 0; nt < 16; ++nt) {
            half4v bf = *(const half4v*)&WDT[(nt * 16 + c) * C + kb * 16 + 4 * g];
            acc[nt] = __builtin_amdgcn_mfma_f32_16x16x16f16(af, bf, acc[nt], 0, 0, 0);
        }
    }
    // second GEMM 256 -> 2: per-lane partials over this lane's 16 hid columns
    float p0[4] = {0.f, 0.f, 0.f, 0.f}, p1[4] = {0.f, 0.f, 0.f, 0.f};
    #pragma unroll
    for (int nt = 0; nt < 16; ++nt) {
        int nn = nt * 16 + c;
        float b = bd[nn];
        float w0 = wo[nn * 2 + 0], w1 = wo[nn * 2 + 1];
        #pragma unroll
        for (int r = 0; r < 4; ++r) {
            float hv = acc[nt][r] + b;
            p0[r] += hv * w0;
            p1[r] += hv * w1;
        }
    }
    #pragma unroll
    for (int m = 1; m <= 8; m <<= 1) {
        #pragma unroll
        for (int r = 0; r < 4; ++r) {
            p0[r] += __shfl_xor(p0[r], m);
            p1[r] += __shfl_xor(p1[r], m);
        }
    }
    if (c == 0) {
        float bo0 = bo[0], bo1 = bo[1];
        #pragma unroll
        for (int r = 0; r < 4; ++r) {
            int node = i0 + w * 16 + 4 * g + r;
            if (node < n) {
                out[(size_t)node * NOUT + 0] = p0[r] + bo0;
                out[(size_t)node * NOUT + 1] = p1[r] + bo1;
            }
        }
    }
}

extern "C" void kernel_launch(void* const* d_in, const int* in_sizes, int n_in,
                              void* d_out, int out_size, void* d_ws, size_t ws_size,
                              hipStream_t stream) {
    const float* x0    = (const float*)d_in[0];
    const int*   ei    = (const int*)d_in[1];
    const float* convW = (const float*)d_in[2];
    const float* wd    = (const float*)d_in[3];
    const float* bd    = (const float*)d_in[4];
    const float* wo    = (const float*)d_in[5];
    const float* bo    = (const float*)d_in[6];
    float* out = (float*)d_out;

    int N = in_sizes[0] / C;
    int E = in_sizes[1] / 2;
    int L = in_sizes[2] / (C * C);
    const int* row = ei;
    const int* col = ei + E;
    int NB = (N + 1023) / 1024;

    char* p = (char*)d_ws;
    auto alloc = [&](size_t bytes) {
        char* r = p;
        p += (bytes + 255) & ~(size_t)255;
        return r;
    };
    int*      cnt    = (int*)alloc((size_t)N * 4);
    int*      offs   = (int*)alloc((size_t)(N + 1) * 4);
    int*      cursor = (int*)alloc((size_t)N * 4);
    int*      bsum   = (int*)alloc((size_t)NB * 4);
    int*      bbase  = (int*)alloc((size_t)NB * 4);
    int2*     csr    = (int2*)alloc((size_t)E * 8);
    float*    dinv   = (float*)alloc((size_t)N * 4);
    __half*   x0h    = (__half*)alloc((size_t)N * C * 2);
    __half*   bufA   = (__half*)alloc((size_t)N * C * 2);
    __half*   bufB   = (__half*)alloc((size_t)N * C * 2);
    _Float16* WT     = (_Float16*)alloc((size_t)L * C * C * 2);
    _Float16* WDT    = (_Float16*)alloc((size_t)256 * C * 2);

    hipMemsetAsync(cnt, 0, (size_t)N * 4, stream);
    count_kernel<<<(E + 255) / 256, 256, 0, stream>>>(col, cnt, E);
    scanA_kernel<<<NB, 1024, 0, stream>>>(cnt, offs, bsum, dinv, N);
    scanB_kernel<<<1, 1024, 0, stream>>>(bsum, bbase, NB);
    scanC_kernel<<<(N + 256) / 256, 256, 0, stream>>>(offs, cursor, bbase, N, E);
    fill_kernel<<<(E + 255) / 256, 256, 0, stream>>>(row, col, dinv, cursor, csr, E);
    convert_kernel<<<(N * 32 + 255) / 256, 256, 0, stream>>>(x0, x0h, N);
    int wtot = L * C * C;
    wtc_kernel<<<(wtot + 255) / 256, 256, 0, stream>>>(convW, WT, wtot);
    wdc_kernel<<<(256 * C + 255) / 256, 256, 0, stream>>>(wd, WDT);

    const __half* xc = x0h;
    for (int l = 0; l < L; ++l) {
        __half* hbuf = (l & 1) ? bufB : bufA;
        agg_kernel<<<(N + 3) / 4, 256, 0, stream>>>(xc, offs, csr, dinv, hbuf, N);
        layer_mfma<<<(N + 63) / 64, 256, 0, stream>>>(hbuf, x0h,
                                                      WT + (size_t)l * C * C, hbuf, N);
        xc = hbuf;
    }
    dense_mfma<<<(N + 63) / 64, 256, 0, stream>>>(xc, WDT, bd, wo, bo, out, N);
}

// Round 8
// 411.860 us; speedup vs baseline: 1.3638x; 1.3638x over previous
//
#include <hip/hip_runtime.h>
#include <hip/hip_fp16.h>

#define C 128
#define NOUT 2
#define ALPHA 0.1f
#define SLOPE 0.01f
#define ZP 136   // padded LDS row stride in halves (272 B, 16B-aligned)

typedef _Float16 half4v __attribute__((ext_vector_type(4)));
typedef float float4v __attribute__((ext_vector_type(4)));

// ---------------- graph preprocessing ----------------

__global__ void count_kernel(const int* __restrict__ col, int* __restrict__ cnt, int E) {
    int e = blockIdx.x * 256 + threadIdx.x;
    if (e < E) atomicAdd(&cnt[col[e]], 1);
}

// per-1024-chunk exclusive scan + chunk totals; also computes dinv
__global__ __launch_bounds__(1024) void scanA_kernel(const int* __restrict__ cnt,
                                                     int* __restrict__ offs,
                                                     int* __restrict__ bsum,
                                                     float* __restrict__ dinv, int n) {
    __shared__ int wsum[16];
    int t = threadIdx.x, lane = t & 63, wv = t >> 6;
    int i = blockIdx.x * 1024 + t;
    int v = (i < n) ? cnt[i] : 0;
    if (i < n) dinv[i] = rsqrtf((float)(v + 1));   // +1 self-loop
    int sc = v;
    #pragma unroll
    for (int d = 1; d < 64; d <<= 1) {
        int u = __shfl_up(sc, d);
        if (lane >= d) sc += u;
    }
    if (lane == 63) wsum[wv] = sc;
    __syncthreads();
    int woff = 0;
    #pragma unroll
    for (int j = 0; j < 16; ++j) woff += (j < wv) ? wsum[j] : 0;
    if (i < n) offs[i] = woff + sc - v;            // block-local exclusive
    if (t == 0) {
        int tot = 0;
        #pragma unroll
        for (int j = 0; j < 16; ++j) tot += wsum[j];
        bsum[blockIdx.x] = tot;
    }
}

__global__ __launch_bounds__(1024) void scanB_kernel(const int* __restrict__ bsum,
                                                     int* __restrict__ bbase, int nb) {
    __shared__ int wsum[16];
    int t = threadIdx.x, lane = t & 63, wv = t >> 6;
    int v = (t < nb) ? bsum[t] : 0;
    int sc = v;
    #pragma unroll
    for (int d = 1; d < 64; d <<= 1) {
        int u = __shfl_up(sc, d);
        if (lane >= d) sc += u;
    }
    if (lane == 63) wsum[wv] = sc;
    __syncthreads();
    int woff = 0;
    #pragma unroll
    for (int j = 0; j < 16; ++j) woff += (j < wv) ? wsum[j] : 0;
    if (t < nb) bbase[t] = woff + sc - v;
}

__global__ void scanC_kernel(int* __restrict__ offs, int* __restrict__ cursor,
                             const int* __restrict__ bbase, int n, int E) {
    int i = blockIdx.x * 256 + threadIdx.x;
    if (i < n) {
        int o = offs[i] + bbase[i >> 10];
        offs[i] = o;
        cursor[i] = o;
    }
    if (i == n) offs[n] = E;
}

// packed edge metadata: {src, float-bits of norm}
__global__ void fill_kernel(const int* __restrict__ row, const int* __restrict__ col,
                            const float* __restrict__ dinv, int* __restrict__ cursor,
                            int2* __restrict__ csr, int E) {
    int e = blockIdx.x * 256 + threadIdx.x;
    if (e >= E) return;
    int r = row[e], c = col[e];
    int pos = atomicAdd(&cursor[c], 1);
    int2 m;
    m.x = r;
    m.y = __float_as_int(dinv[r] * dinv[c]);
    csr[pos] = m;
}

// fp32 node-major -> fp16 node-major
__global__ __launch_bounds__(256) void convert_kernel(const float* __restrict__ x,
                                                      __half* __restrict__ xh, int n) {
    int g = blockIdx.x * 256 + threadIdx.x;
    if (g >= n * 32) return;
    float4 v = ((const float4*)x)[g];
    union { __half2 h; unsigned u; } a, b;
    a.h = __float22half2_rn(make_float2(v.x, v.y));
    b.h = __float22half2_rn(make_float2(v.z, v.w));
    ((uint2*)xh)[g] = make_uint2(a.u, b.u);
}

// conv weights: fp32 [l][k][n] -> fp16 [l][n][k]
__global__ void wtc_kernel(const float* __restrict__ W, _Float16* __restrict__ WT, int total) {
    int idx = blockIdx.x * 256 + threadIdx.x;
    if (idx >= total) return;
    int l = idx >> 14, rem = idx & 16383;
    int nrow = rem >> 7, kk = rem & 127;
    WT[idx] = (_Float16)W[(l << 14) + kk * C + nrow];
}

// dense weights: fp32 [k][256] -> fp16 [256][k]
__global__ void wdc_kernel(const float* __restrict__ wd, _Float16* __restrict__ WDT) {
    int idx = blockIdx.x * 256 + threadIdx.x;
    if (idx >= 256 * C) return;
    int nrow = idx >> 7, kk = idx & 127;
    WDT[idx] = (_Float16)wd[kk * 256 + nrow];
}

__device__ __forceinline__ void accum8(float* a, uint4 q, float w) {
    union { unsigned u; __half2 h; } c;
    float2 f;
    c.u = q.x; f = __half22float2(c.h); a[0] += w * f.x; a[1] += w * f.y;
    c.u = q.y; f = __half22float2(c.h); a[2] += w * f.x; a[3] += w * f.y;
    c.u = q.z; f = __half22float2(c.h); a[4] += w * f.x; a[5] += w * f.y;
    c.u = q.w; f = __half22float2(c.h); a[6] += w * f.x; a[7] += w * f.y;
}

__device__ __forceinline__ uint4 pack8(const float* a) {
    union { __half2 h; unsigned u; } c0, c1, c2, c3;
    c0.h = __float22half2_rn(make_float2(a[0], a[1]));
    c1.h = __float22half2_rn(make_float2(a[2], a[3]));
    c2.h = __float22half2_rn(make_float2(a[4], a[5]));
    c3.h = __float22half2_rn(make_float2(a[6], a[7]));
    return make_uint4(c0.u, c1.u, c2.u, c3.u);
}

// ---------------- aggregation: one wave per node; eslot(0..3) x cg(0..15) uint4 lanes;
// unroll-4 -> 16 x 16B gathers in flight per wave
__global__ __launch_bounds__(256) void agg_kernel(
    const __half* __restrict__ xc, const int* __restrict__ offs,
    const int2* __restrict__ csr, const float* __restrict__ dinv,
    __half* __restrict__ h, int n)
{
    int node = blockIdx.x * 4 + (threadIdx.x >> 6);
    if (node >= n) return;
    int lane = threadIdx.x & 63;
    int eslot = lane >> 4, cg = lane & 15;
    const uint4* x4 = (const uint4*)xc;
    float a0[8] = {}, a1[8] = {}, a2[8] = {}, a3[8] = {};
    int beg = offs[node], end = offs[node + 1];
    int k = beg + eslot;
    for (; k + 12 < end; k += 16) {
        int2 m0 = csr[k], m1 = csr[k + 4], m2 = csr[k + 8], m3 = csr[k + 12];
        uint4 q0 = x4[(size_t)m0.x * 16 + cg];
        uint4 q1 = x4[(size_t)m1.x * 16 + cg];
        uint4 q2 = x4[(size_t)m2.x * 16 + cg];
        uint4 q3 = x4[(size_t)m3.x * 16 + cg];
        accum8(a0, q0, __int_as_float(m0.y));
        accum8(a1, q1, __int_as_float(m1.y));
        accum8(a2, q2, __int_as_float(m2.y));
        accum8(a3, q3, __int_as_float(m3.y));
    }
    for (; k < end; k += 4) {
        int2 m = csr[k];
        uint4 q = x4[(size_t)m.x * 16 + cg];
        accum8(a0, q, __int_as_float(m.y));
    }
    #pragma unroll
    for (int j = 0; j < 8; ++j) a0[j] += a1[j] + a2[j] + a3[j];
    #pragma unroll
    for (int j = 0; j < 8; ++j) {
        a0[j] += __shfl_xor(a0[j], 16);
        a0[j] += __shfl_xor(a0[j], 32);
    }
    if (eslot == 0) {
        float di = dinv[node], sw = di * di;
        uint4 qs = x4[(size_t)node * 16 + cg];
        accum8(a0, qs, sw);
        ((uint4*)h)[(size_t)node * 16 + cg] = pack8(a0);
    }
}

// ---------------- layer GEMM (MFMA, B-in-registers): xn = leaky(((1-a)h+a*x0)@W)
// 64 nodes/block, 4 waves; wave w owns cols [32w,32w+32) (2 n-tiles), all 64 rows.
// B frags (16 per wave, 32 VGPR) hoisted once; A frags from LDS; out via LDS repack.
__global__ __launch_bounds__(256) void layer_mfma(
    const __half* __restrict__ hbuf, const __half* __restrict__ x0h,
    const _Float16* __restrict__ WT, __half* __restrict__ xn, int n)
{
    __shared__ _Float16 zl[64 * ZP];
    __shared__ _Float16 ol[64 * ZP];
    int i0 = blockIdx.x * 64;
    int t = threadIdx.x;
    int w = t >> 6, lane = t & 63;
    int c = lane & 15, g = lane >> 4;

    // stage z = (1-a)h + a*x0 (fp16), 16B per thread-iter
    const uint4* h4 = (const uint4*)hbuf;
    const uint4* x4 = (const uint4*)x0h;
    for (int p = t; p < 64 * 16; p += 256) {
        int r = p >> 4, c8 = p & 15;
        uint4 zv = make_uint4(0, 0, 0, 0);
        if (i0 + r < n) {
            uint4 hv = h4[(size_t)(i0 + r) * 16 + c8];
            uint4 xv = x4[(size_t)(i0 + r) * 16 + c8];
            const __half2* hp = (const __half2*)&hv;
            const __half2* xp = (const __half2*)&xv;
            __half2* zp = (__half2*)&zv;
            #pragma unroll
            for (int j = 0; j < 4; ++j) {
                float2 hf = __half22float2(hp[j]);
                float2 xf = __half22float2(xp[j]);
                zp[j] = __float22half2_rn(make_float2(
                    (1.f - ALPHA) * hf.x + ALPHA * xf.x,
                    (1.f - ALPHA) * hf.y + ALPHA * xf.y));
            }
        }
        *(uint4*)&zl[r * ZP + c8 * 8] = zv;
    }

    // hoist B fragments for this wave's 2 n-tiles (L2-hot after first blocks)
    half4v bf[8][2];
    #pragma unroll
    for (int kb = 0; kb < 8; ++kb)
        #pragma unroll
        for (int nt = 0; nt < 2; ++nt)
            bf[kb][nt] = *(const half4v*)&WT[((w * 2 + nt) * 16 + c) * C + kb * 16 + 4 * g];

    __syncthreads();

    #pragma unroll
    for (int m = 0; m < 4; ++m) {
        const _Float16* arow = &zl[(m * 16 + c) * ZP];
        half4v af[8];
        #pragma unroll
        for (int kb = 0; kb < 8; ++kb) af[kb] = *(const half4v*)&arow[kb * 16 + 4 * g];
        float4v acc0 = (float4v)0.f, acc1 = (float4v)0.f;
        #pragma unroll
        for (int kb = 0; kb < 8; ++kb) {
            acc0 = __builtin_amdgcn_mfma_f32_16x16x16f16(af[kb], bf[kb][0], acc0, 0, 0, 0);
            acc1 = __builtin_amdgcn_mfma_f32_16x16x16f16(af[kb], bf[kb][1], acc1, 0, 0, 0);
        }
        #pragma unroll
        for (int r = 0; r < 4; ++r) {
            float v0 = acc0[r]; v0 = v0 > 0.f ? v0 : SLOPE * v0;
            float v1 = acc1[r]; v1 = v1 > 0.f ? v1 : SLOPE * v1;
            ol[(m * 16 + 4 * g + r) * ZP + (w * 2 + 0) * 16 + c] = (_Float16)v0;
            ol[(m * 16 + 4 * g + r) * ZP + (w * 2 + 1) * 16 + c] = (_Float16)v1;
        }
    }
    __syncthreads();
    for (int p = t; p < 64 * 16; p += 256) {
        int r = p >> 4, c8 = p & 15;
        int node = i0 + r;
        if (node < n)
            ((uint4*)xn)[(size_t)node * 16 + c8] = *(uint4*)&ol[r * ZP + c8 * 8];
    }
}

// ---------------- dense head (MFMA, B-in-registers): out = (x@wd + bd) @ wo + bo
// 64 nodes/block, 4 waves; wave w owns hid cols [64w,64w+64) (4 n-tiles), all rows.
__global__ __launch_bounds__(256) void dense_mfma(
    const __half* __restrict__ xin, const _Float16* __restrict__ WDT,
    const float* __restrict__ bd, const float* __restrict__ wo,
    const float* __restrict__ bo, float* __restrict__ out, int n)
{
    __shared__ _Float16 xl[64 * ZP];
    __shared__ float pp[64][4][2];
    int i0 = blockIdx.x * 64;
    int t = threadIdx.x;
    int w = t >> 6, lane = t & 63;
    int c = lane & 15, g = lane >> 4;

    const uint4* g4 = (const uint4*)xin;
    for (int p = t; p < 64 * 16; p += 256) {
        int r = p >> 4, c8 = p & 15;
        uint4 v = make_uint4(0, 0, 0, 0);
        if (i0 + r < n) v = g4[(size_t)(i0 + r) * 16 + c8];
        *(uint4*)&xl[r * ZP + c8 * 8] = v;
    }

    // hoist B fragments (4 n-tiles) + second-stage weights
    half4v bf[8][4];
    #pragma unroll
    for (int kb = 0; kb < 8; ++kb)
        #pragma unroll
        for (int nt = 0; nt < 4; ++nt)
            bf[kb][nt] = *(const half4v*)&WDT[((w * 4 + nt) * 16 + c) * C + kb * 16 + 4 * g];
    float bdv[4], wo0[4], wo1[4];
    #pragma unroll
    for (int nt = 0; nt < 4; ++nt) {
        int coln = (w * 4 + nt) * 16 + c;
        bdv[nt] = bd[coln];
        wo0[nt] = wo[coln * 2 + 0];
        wo1[nt] = wo[coln * 2 + 1];
    }

    __syncthreads();

    #pragma unroll
    for (int m = 0; m < 4; ++m) {
        const _Float16* arow = &xl[(m * 16 + c) * ZP];
        half4v af[8];
        #pragma unroll
        for (int kb = 0; kb < 8; ++kb) af[kb] = *(const half4v*)&arow[kb * 16 + 4 * g];
        float4v acc[4];
        #pragma unroll
        for (int nt = 0; nt < 4; ++nt) acc[nt] = (float4v)0.f;
        #pragma unroll
        for (int kb = 0; kb < 8; ++kb) {
            #pragma unroll
            for (int nt = 0; nt < 4; ++nt)
                acc[nt] = __builtin_amdgcn_mfma_f32_16x16x16f16(af[kb], bf[kb][nt], acc[nt], 0, 0, 0);
        }
        // second GEMM partials over this wave's 64 hid cols
        float p0[4] = {0.f, 0.f, 0.f, 0.f}, p1[4] = {0.f, 0.f, 0.f, 0.f};
        #pragma unroll
        for (int nt = 0; nt < 4; ++nt) {
            #pragma unroll
            for (int r = 0; r < 4; ++r) {
                float hv = acc[nt][r] + bdv[nt];
                p0[r] += hv * wo0[nt];
                p1[r] += hv * wo1[nt];
            }
        }
        #pragma unroll
        for (int ms = 1; ms <= 8; ms <<= 1) {
            #pragma unroll
            for (int r = 0; r < 4; ++r) {
                p0[r] += __shfl_xor(p0[r], ms);
                p1[r] += __shfl_xor(p1[r], ms);
            }
        }
        if (c == 0) {
            #pragma unroll
            for (int r = 0; r < 4; ++r) {
                pp[m * 16 + 4 * g + r][w][0] = p0[r];
                pp[m * 16 + 4 * g + r][w][1] = p1[r];
            }
        }
    }
    __syncthreads();
    if (t < 128) {
        int r = t >> 1, o = t & 1;
        int node = i0 + r;
        if (node < n) {
            float s = pp[r][0][o] + pp[r][1][o] + pp[r][2][o] + pp[r][3][o];
            out[(size_t)node * NOUT + o] = s + bo[o];
        }
    }
}

extern "C" void kernel_launch(void* const* d_in, const int* in_sizes, int n_in,
                              void* d_out, int out_size, void* d_ws, size_t ws_size,
                              hipStream_t stream) {
    const float* x0    = (const float*)d_in[0];
    const int*   ei    = (const int*)d_in[1];
    const float* convW = (const float*)d_in[2];
    const float* wd    = (const float*)d_in[3];
    const float* bd    = (const float*)d_in[4];
    const float* wo    = (const float*)d_in[5];
    const float* bo    = (const float*)d_in[6];
    float* out = (float*)d_out;

    int N = in_sizes[0] / C;
    int E = in_sizes[1] / 2;
    int L = in_sizes[2] / (C * C);
    const int* row = ei;
    const int* col = ei + E;
    int NB = (N + 1023) / 1024;

    char* p = (char*)d_ws;
    auto alloc = [&](size_t bytes) {
        char* r = p;
        p += (bytes + 255) & ~(size_t)255;
        return r;
    };
    int*      cnt    = (int*)alloc((size_t)N * 4);
    int*      offs   = (int*)alloc((size_t)(N + 1) * 4);
    int*      cursor = (int*)alloc((size_t)N * 4);
    int*      bsum   = (int*)alloc((size_t)NB * 4);
    int*      bbase  = (int*)alloc((size_t)NB * 4);
    int2*     csr    = (int2*)alloc((size_t)E * 8);
    float*    dinv   = (float*)alloc((size_t)N * 4);
    __half*   x0h    = (__half*)alloc((size_t)N * C * 2);
    __half*   bufA   = (__half*)alloc((size_t)N * C * 2);
    __half*   bufB   = (__half*)alloc((size_t)N * C * 2);
    _Float16* WT     = (_Float16*)alloc((size_t)L * C * C * 2);
    _Float16* WDT    = (_Float16*)alloc((size_t)256 * C * 2);

    hipMemsetAsync(cnt, 0, (size_t)N * 4, stream);
    count_kernel<<<(E + 255) / 256, 256, 0, stream>>>(col, cnt, E);
    scanA_kernel<<<NB, 1024, 0, stream>>>(cnt, offs, bsum, dinv, N);
    scanB_kernel<<<1, 1024, 0, stream>>>(bsum, bbase, NB);
    scanC_kernel<<<(N + 256) / 256, 256, 0, stream>>>(offs, cursor, bbase, N, E);
    fill_kernel<<<(E + 255) / 256, 256, 0, stream>>>(row, col, dinv, cursor, csr, E);
    convert_kernel<<<(N * 32 + 255) / 256, 256, 0, stream>>>(x0, x0h, N);
    int wtot = L * C * C;
    wtc_kernel<<<(wtot + 255) / 256, 256, 0, stream>>>(convW, WT, wtot);
    wdc_kernel<<<(256 * C + 255) / 256, 256, 0, stream>>>(wd, WDT);

    const __half* xc = x0h;
    for (int l = 0; l < L; ++l) {
        __half* hbuf = (l & 1) ? bufB : bufA;
        agg_kernel<<<(N + 3) / 4, 256, 0, stream>>>(xc, offs, csr, dinv, hbuf, N);
        layer_mfma<<<(N + 63) / 64, 256, 0, stream>>>(hbuf, x0h,
                                                      WT + (size_t)l * C * C, hbuf, N);
        xc = hbuf;
    }
    dense_mfma<<<(N + 63) / 64, 256, 0, stream>>>(xc, WDT, bd, wo, bo, out, N);
}

// Round 9
// 411.634 us; speedup vs baseline: 1.3646x; 1.0005x over previous
//
#include <hip/hip_runtime.h>
#include <hip/hip_fp16.h>

#define C 128
#define NOUT 2
#define ALPHA 0.1f
#define SLOPE 0.01f
#define ZP 136   // padded LDS row stride in halves (272 B, 16B-aligned)

typedef _Float16 half4v __attribute__((ext_vector_type(4)));
typedef float float4v __attribute__((ext_vector_type(4)));

// ---------------- graph preprocessing ----------------

__global__ void count_kernel(const int* __restrict__ col, int* __restrict__ cnt, int E) {
    int e = blockIdx.x * 256 + threadIdx.x;
    if (e < E) atomicAdd(&cnt[col[e]], 1);
}

// per-1024-chunk exclusive scan + chunk totals; also computes dinv
__global__ __launch_bounds__(1024) void scanA_kernel(const int* __restrict__ cnt,
                                                     int* __restrict__ offs,
                                                     int* __restrict__ bsum,
                                                     float* __restrict__ dinv, int n) {
    __shared__ int wsum[16];
    int t = threadIdx.x, lane = t & 63, wv = t >> 6;
    int i = blockIdx.x * 1024 + t;
    int v = (i < n) ? cnt[i] : 0;
    if (i < n) dinv[i] = rsqrtf((float)(v + 1));   // +1 self-loop
    int sc = v;
    #pragma unroll
    for (int d = 1; d < 64; d <<= 1) {
        int u = __shfl_up(sc, d);
        if (lane >= d) sc += u;
    }
    if (lane == 63) wsum[wv] = sc;
    __syncthreads();
    int woff = 0;
    #pragma unroll
    for (int j = 0; j < 16; ++j) woff += (j < wv) ? wsum[j] : 0;
    if (i < n) offs[i] = woff + sc - v;            // block-local exclusive
    if (t == 0) {
        int tot = 0;
        #pragma unroll
        for (int j = 0; j < 16; ++j) tot += wsum[j];
        bsum[blockIdx.x] = tot;
    }
}

__global__ __launch_bounds__(1024) void scanB_kernel(const int* __restrict__ bsum,
                                                     int* __restrict__ bbase, int nb) {
    __shared__ int wsum[16];
    int t = threadIdx.x, lane = t & 63, wv = t >> 6;
    int v = (t < nb) ? bsum[t] : 0;
    int sc = v;
    #pragma unroll
    for (int d = 1; d < 64; d <<= 1) {
        int u = __shfl_up(sc, d);
        if (lane >= d) sc += u;
    }
    if (lane == 63) wsum[wv] = sc;
    __syncthreads();
    int woff = 0;
    #pragma unroll
    for (int j = 0; j < 16; ++j) woff += (j < wv) ? wsum[j] : 0;
    if (t < nb) bbase[t] = woff + sc - v;
}

__global__ void scanC_kernel(int* __restrict__ offs, int* __restrict__ cursor,
                             const int* __restrict__ bbase, int n, int E) {
    int i = blockIdx.x * 256 + threadIdx.x;
    if (i < n) {
        int o = offs[i] + bbase[i >> 10];
        offs[i] = o;
        cursor[i] = o;
    }
    if (i == n) offs[n] = E;
}

// packed edge metadata: (src << 16) | fp16-bits(norm). REQUIRES n < 65536.
// 4 independent edges per thread -> 4 atomic chains in flight.
__global__ void fill_kernel(const int* __restrict__ row, const int* __restrict__ col,
                            const float* __restrict__ dinv, int* __restrict__ cursor,
                            unsigned* __restrict__ csr, int E) {
    int base = blockIdx.x * 1024 + threadIdx.x;
    int r[4], c[4];
    bool v[4];
    #pragma unroll
    for (int j = 0; j < 4; ++j) {
        int e = base + j * 256;
        v[j] = e < E;
        r[j] = v[j] ? row[e] : 0;
        c[j] = v[j] ? col[e] : 0;
    }
    float nr[4];
    #pragma unroll
    for (int j = 0; j < 4; ++j) nr[j] = dinv[r[j]] * dinv[c[j]];
    int pos[4];
    #pragma unroll
    for (int j = 0; j < 4; ++j)
        pos[j] = v[j] ? atomicAdd(&cursor[c[j]], 1) : 0;
    #pragma unroll
    for (int j = 0; j < 4; ++j) {
        if (v[j]) {
            union { __half h; unsigned short u; } nh;
            nh.h = __float2half_rn(nr[j]);
            csr[pos[j]] = ((unsigned)r[j] << 16) | (unsigned)nh.u;
        }
    }
}

// fp32 node-major -> fp16 node-major
__global__ __launch_bounds__(256) void convert_kernel(const float* __restrict__ x,
                                                      __half* __restrict__ xh, int n) {
    int g = blockIdx.x * 256 + threadIdx.x;
    if (g >= n * 32) return;
    float4 v = ((const float4*)x)[g];
    union { __half2 h; unsigned u; } a, b;
    a.h = __float22half2_rn(make_float2(v.x, v.y));
    b.h = __float22half2_rn(make_float2(v.z, v.w));
    ((uint2*)xh)[g] = make_uint2(a.u, b.u);
}

// conv weights: fp32 [l][k][n] -> fp16 [l][n][k]
__global__ void wtc_kernel(const float* __restrict__ W, _Float16* __restrict__ WT, int total) {
    int idx = blockIdx.x * 256 + threadIdx.x;
    if (idx >= total) return;
    int l = idx >> 14, rem = idx & 16383;
    int nrow = rem >> 7, kk = rem & 127;
    WT[idx] = (_Float16)W[(l << 14) + kk * C + nrow];
}

// dense weights: fp32 [k][256] -> fp16 [256][k]
__global__ void wdc_kernel(const float* __restrict__ wd, _Float16* __restrict__ WDT) {
    int idx = blockIdx.x * 256 + threadIdx.x;
    if (idx >= 256 * C) return;
    int nrow = idx >> 7, kk = idx & 127;
    WDT[idx] = (_Float16)wd[kk * 256 + nrow];
}

__device__ __forceinline__ void accum8(float* a, uint4 q, float w) {
    union { unsigned u; __half2 h; } c;
    float2 f;
    c.u = q.x; f = __half22float2(c.h); a[0] += w * f.x; a[1] += w * f.y;
    c.u = q.y; f = __half22float2(c.h); a[2] += w * f.x; a[3] += w * f.y;
    c.u = q.z; f = __half22float2(c.h); a[4] += w * f.x; a[5] += w * f.y;
    c.u = q.w; f = __half22float2(c.h); a[6] += w * f.x; a[7] += w * f.y;
}

__device__ __forceinline__ uint4 pack8(const float* a) {
    union { __half2 h; unsigned u; } c0, c1, c2, c3;
    c0.h = __float22half2_rn(make_float2(a[0], a[1]));
    c1.h = __float22half2_rn(make_float2(a[2], a[3]));
    c2.h = __float22half2_rn(make_float2(a[4], a[5]));
    c3.h = __float22half2_rn(make_float2(a[6], a[7]));
    return make_uint4(c0.u, c1.u, c2.u, c3.u);
}

__device__ __forceinline__ float norm_of(unsigned m) {
    union { unsigned short u; __half h; } nh;
    nh.u = (unsigned short)(m & 0xffffu);
    return __half2float(nh.h);
}

// ---------------- aggregation + residual: z[i] = (1-a)(sum_j norm*x[j] + dinv^2*x[i]) + a*x0[i]
// one wave per node; eslot(0..3) x cg(0..15) uint4 lanes; unroll-4 -> 16 gathers in flight
__global__ __launch_bounds__(256) void agg_kernel(
    const __half* __restrict__ xc, const __half* __restrict__ x0h,
    const int* __restrict__ offs, const unsigned* __restrict__ csr,
    const float* __restrict__ dinv, __half* __restrict__ z, int n)
{
    int node = blockIdx.x * 4 + (threadIdx.x >> 6);
    if (node >= n) return;
    int lane = threadIdx.x & 63;
    int eslot = lane >> 4, cg = lane & 15;
    const uint4* x4 = (const uint4*)xc;
    float a0[8] = {}, a1[8] = {}, a2[8] = {}, a3[8] = {};
    int beg = offs[node], end = offs[node + 1];
    int k = beg + eslot;
    for (; k + 12 < end; k += 16) {
        unsigned m0 = csr[k], m1 = csr[k + 4], m2 = csr[k + 8], m3 = csr[k + 12];
        uint4 q0 = x4[(size_t)(m0 >> 16) * 16 + cg];
        uint4 q1 = x4[(size_t)(m1 >> 16) * 16 + cg];
        uint4 q2 = x4[(size_t)(m2 >> 16) * 16 + cg];
        uint4 q3 = x4[(size_t)(m3 >> 16) * 16 + cg];
        accum8(a0, q0, norm_of(m0));
        accum8(a1, q1, norm_of(m1));
        accum8(a2, q2, norm_of(m2));
        accum8(a3, q3, norm_of(m3));
    }
    for (; k < end; k += 4) {
        unsigned m = csr[k];
        uint4 q = x4[(size_t)(m >> 16) * 16 + cg];
        accum8(a0, q, norm_of(m));
    }
    #pragma unroll
    for (int j = 0; j < 8; ++j) a0[j] += a1[j] + a2[j] + a3[j];
    #pragma unroll
    for (int j = 0; j < 8; ++j) {
        a0[j] += __shfl_xor(a0[j], 16);
        a0[j] += __shfl_xor(a0[j], 32);
    }
    if (eslot == 0) {
        float di = dinv[node], sw = di * di;
        uint4 qs = x4[(size_t)node * 16 + cg];
        accum8(a0, qs, sw);
        uint4 q0x = ((const uint4*)x0h)[(size_t)node * 16 + cg];
        float xr[8] = {};
        accum8(xr, q0x, 1.f);
        float zz[8];
        #pragma unroll
        for (int j = 0; j < 8; ++j) zz[j] = (1.f - ALPHA) * a0[j] + ALPHA * xr[j];
        ((uint4*)z)[(size_t)node * 16 + cg] = pack8(zz);
    }
}

// ---------------- layer GEMM (MFMA, B-in-registers): xn = leaky(z @ W)
// 64 nodes/block, 4 waves; wave w owns cols [32w,32w+32) (2 n-tiles), all 64 rows.
__global__ __launch_bounds__(256) void layer_mfma(
    const __half* __restrict__ zin, const _Float16* __restrict__ WT,
    __half* __restrict__ xn, int n)
{
    __shared__ _Float16 zl[64 * ZP];
    __shared__ _Float16 ol[64 * ZP];
    int i0 = blockIdx.x * 64;
    int t = threadIdx.x;
    int w = t >> 6, lane = t & 63;
    int c = lane & 15, g = lane >> 4;

    const uint4* z4 = (const uint4*)zin;
    for (int p = t; p < 64 * 16; p += 256) {
        int r = p >> 4, c8 = p & 15;
        uint4 zv = make_uint4(0, 0, 0, 0);
        if (i0 + r < n) zv = z4[(size_t)(i0 + r) * 16 + c8];
        *(uint4*)&zl[r * ZP + c8 * 8] = zv;
    }

    // hoist B fragments for this wave's 2 n-tiles
    half4v bf[8][2];
    #pragma unroll
    for (int kb = 0; kb < 8; ++kb)
        #pragma unroll
        for (int nt = 0; nt < 2; ++nt)
            bf[kb][nt] = *(const half4v*)&WT[((w * 2 + nt) * 16 + c) * C + kb * 16 + 4 * g];

    __syncthreads();

    #pragma unroll
    for (int m = 0; m < 4; ++m) {
        const _Float16* arow = &zl[(m * 16 + c) * ZP];
        half4v af[8];
        #pragma unroll
        for (int kb = 0; kb < 8; ++kb) af[kb] = *(const half4v*)&arow[kb * 16 + 4 * g];
        float4v acc0 = (float4v)0.f, acc1 = (float4v)0.f;
        #pragma unroll
        for (int kb = 0; kb < 8; ++kb) {
            acc0 = __builtin_amdgcn_mfma_f32_16x16x16f16(af[kb], bf[kb][0], acc0, 0, 0, 0);
            acc1 = __builtin_amdgcn_mfma_f32_16x16x16f16(af[kb], bf[kb][1], acc1, 0, 0, 0);
        }
        #pragma unroll
        for (int r = 0; r < 4; ++r) {
            float v0 = acc0[r]; v0 = v0 > 0.f ? v0 : SLOPE * v0;
            float v1 = acc1[r]; v1 = v1 > 0.f ? v1 : SLOPE * v1;
            ol[(m * 16 + 4 * g + r) * ZP + (w * 2 + 0) * 16 + c] = (_Float16)v0;
            ol[(m * 16 + 4 * g + r) * ZP + (w * 2 + 1) * 16 + c] = (_Float16)v1;
        }
    }
    __syncthreads();
    for (int p = t; p < 64 * 16; p += 256) {
        int r = p >> 4, c8 = p & 15;
        int node = i0 + r;
        if (node < n)
            ((uint4*)xn)[(size_t)node * 16 + c8] = *(uint4*)&ol[r * ZP + c8 * 8];
    }
}

// ---------------- dense head (MFMA, B-in-registers): out = (x@wd + bd) @ wo + bo
__global__ __launch_bounds__(256) void dense_mfma(
    const __half* __restrict__ xin, const _Float16* __restrict__ WDT,
    const float* __restrict__ bd, const float* __restrict__ wo,
    const float* __restrict__ bo, float* __restrict__ out, int n)
{
    __shared__ _Float16 xl[64 * ZP];
    __shared__ float pp[64][4][2];
    int i0 = blockIdx.x * 64;
    int t = threadIdx.x;
    int w = t >> 6, lane = t & 63;
    int c = lane & 15, g = lane >> 4;

    const uint4* g4 = (const uint4*)xin;
    for (int p = t; p < 64 * 16; p += 256) {
        int r = p >> 4, c8 = p & 15;
        uint4 v = make_uint4(0, 0, 0, 0);
        if (i0 + r < n) v = g4[(size_t)(i0 + r) * 16 + c8];
        *(uint4*)&xl[r * ZP + c8 * 8] = v;
    }

    half4v bf[8][4];
    #pragma unroll
    for (int kb = 0; kb < 8; ++kb)
        #pragma unroll
        for (int nt = 0; nt < 4; ++nt)
            bf[kb][nt] = *(const half4v*)&WDT[((w * 4 + nt) * 16 + c) * C + kb * 16 + 4 * g];
    float bdv[4], wo0[4], wo1[4];
    #pragma unroll
    for (int nt = 0; nt < 4; ++nt) {
        int coln = (w * 4 + nt) * 16 + c;
        bdv[nt] = bd[coln];
        wo0[nt] = wo[coln * 2 + 0];
        wo1[nt] = wo[coln * 2 + 1];
    }

    __syncthreads();

    #pragma unroll
    for (int m = 0; m < 4; ++m) {
        const _Float16* arow = &xl[(m * 16 + c) * ZP];
        half4v af[8];
        #pragma unroll
        for (int kb = 0; kb < 8; ++kb) af[kb] = *(const half4v*)&arow[kb * 16 + 4 * g];
        float4v acc[4];
        #pragma unroll
        for (int nt = 0; nt < 4; ++nt) acc[nt] = (float4v)0.f;
        #pragma unroll
        for (int kb = 0; kb < 8; ++kb) {
            #pragma unroll
            for (int nt = 0; nt < 4; ++nt)
                acc[nt] = __builtin_amdgcn_mfma_f32_16x16x16f16(af[kb], bf[kb][nt], acc[nt], 0, 0, 0);
        }
        float p0[4] = {0.f, 0.f, 0.f, 0.f}, p1[4] = {0.f, 0.f, 0.f, 0.f};
        #pragma unroll
        for (int nt = 0; nt < 4; ++nt) {
            #pragma unroll
            for (int r = 0; r < 4; ++r) {
                float hv = acc[nt][r] + bdv[nt];
                p0[r] += hv * wo0[nt];
                p1[r] += hv * wo1[nt];
            }
        }
        #pragma unroll
        for (int ms = 1; ms <= 8; ms <<= 1) {
            #pragma unroll
            for (int r = 0; r < 4; ++r) {
                p0[r] += __shfl_xor(p0[r], ms);
                p1[r] += __shfl_xor(p1[r], ms);
            }
        }
        if (c == 0) {
            #pragma unroll
            for (int r = 0; r < 4; ++r) {
                pp[m * 16 + 4 * g + r][w][0] = p0[r];
                pp[m * 16 + 4 * g + r][w][1] = p1[r];
            }
        }
    }
    __syncthreads();
    if (t < 128) {
        int r = t >> 1, o = t & 1;
        int node = i0 + r;
        if (node < n) {
            float s = pp[r][0][o] + pp[r][1][o] + pp[r][2][o] + pp[r][3][o];
            out[(size_t)node * NOUT + o] = s + bo[o];
        }
    }
}

extern "C" void kernel_launch(void* const* d_in, const int* in_sizes, int n_in,
                              void* d_out, int out_size, void* d_ws, size_t ws_size,
                              hipStream_t stream) {
    const float* x0    = (const float*)d_in[0];
    const int*   ei    = (const int*)d_in[1];
    const float* convW = (const float*)d_in[2];
    const float* wd    = (const float*)d_in[3];
    const float* bd    = (const float*)d_in[4];
    const float* wo    = (const float*)d_in[5];
    const float* bo    = (const float*)d_in[6];
    float* out = (float*)d_out;

    int N = in_sizes[0] / C;
    int E = in_sizes[1] / 2;
    int L = in_sizes[2] / (C * C);
    const int* row = ei;
    const int* col = ei + E;
    int NB = (N + 1023) / 1024;

    char* p = (char*)d_ws;
    auto alloc = [&](size_t bytes) {
        char* r = p;
        p += (bytes + 255) & ~(size_t)255;
        return r;
    };
    int*      cnt    = (int*)alloc((size_t)N * 4);
    int*      offs   = (int*)alloc((size_t)(N + 1) * 4);
    int*      cursor = (int*)alloc((size_t)N * 4);
    int*      bsum   = (int*)alloc((size_t)NB * 4);
    int*      bbase  = (int*)alloc((size_t)NB * 4);
    unsigned* csr    = (unsigned*)alloc((size_t)E * 4);
    float*    dinv   = (float*)alloc((size_t)N * 4);
    __half*   x0h    = (__half*)alloc((size_t)N * C * 2);
    __half*   bufA   = (__half*)alloc((size_t)N * C * 2);
    __half*   zbuf   = (__half*)alloc((size_t)N * C * 2);
    _Float16* WT     = (_Float16*)alloc((size_t)L * C * C * 2);
    _Float16* WDT    = (_Float16*)alloc((size_t)256 * C * 2);

    hipMemsetAsync(cnt, 0, (size_t)N * 4, stream);
    count_kernel<<<(E + 255) / 256, 256, 0, stream>>>(col, cnt, E);
    scanA_kernel<<<NB, 1024, 0, stream>>>(cnt, offs, bsum, dinv, N);
    scanB_kernel<<<1, 1024, 0, stream>>>(bsum, bbase, NB);
    scanC_kernel<<<(N + 256) / 256, 256, 0, stream>>>(offs, cursor, bbase, N, E);
    fill_kernel<<<(E + 1023) / 1024, 256, 0, stream>>>(row, col, dinv, cursor, csr, E);
    convert_kernel<<<(N * 32 + 255) / 256, 256, 0, stream>>>(x0, x0h, N);
    int wtot = L * C * C;
    wtc_kernel<<<(wtot + 255) / 256, 256, 0, stream>>>(convW, WT, wtot);
    wdc_kernel<<<(256 * C + 255) / 256, 256, 0, stream>>>(wd, WDT);

    const __half* xc = x0h;
    for (int l = 0; l < L; ++l) {
        agg_kernel<<<(N + 3) / 4, 256, 0, stream>>>(xc, x0h, offs, csr, dinv, zbuf, N);
        layer_mfma<<<(N + 63) / 64, 256, 0, stream>>>(zbuf, WT + (size_t)l * C * C,
                                                      bufA, N);
        xc = bufA;
    }
    dense_mfma<<<(N + 63) / 64, 256, 0, stream>>>(xc, WDT, bd, wo, bo, out, N);
}

// Round 10
// 365.785 us; speedup vs baseline: 1.5356x; 1.1253x over previous
//
#include <hip/hip_runtime.h>
#include <hip/hip_fp16.h>

#define C 128
#define NOUT 2
#define ALPHA 0.1f
#define SLOPE 0.01f
#define ZP 136   // padded LDS row stride in halves (272 B, 16B-aligned)

typedef _Float16 half4v __attribute__((ext_vector_type(4)));
typedef float float4v __attribute__((ext_vector_type(4)));

// ---------------- graph preprocessing ----------------

// counts per destination AND per-edge rank (return of the atomic) in one pass
__global__ void count_kernel(const int* __restrict__ col, int* __restrict__ cnt,
                             int* __restrict__ rank, int E) {
    int e = blockIdx.x * 256 + threadIdx.x;
    if (e < E) rank[e] = atomicAdd(&cnt[col[e]], 1);
}

// per-1024-chunk exclusive scan + chunk totals; also computes dinv
__global__ __launch_bounds__(1024) void scanA_kernel(const int* __restrict__ cnt,
                                                     int* __restrict__ offs,
                                                     int* __restrict__ bsum,
                                                     float* __restrict__ dinv, int n) {
    __shared__ int wsum[16];
    int t = threadIdx.x, lane = t & 63, wv = t >> 6;
    int i = blockIdx.x * 1024 + t;
    int v = (i < n) ? cnt[i] : 0;
    if (i < n) dinv[i] = rsqrtf((float)(v + 1));   // +1 self-loop
    int sc = v;
    #pragma unroll
    for (int d = 1; d < 64; d <<= 1) {
        int u = __shfl_up(sc, d);
        if (lane >= d) sc += u;
    }
    if (lane == 63) wsum[wv] = sc;
    __syncthreads();
    int woff = 0;
    #pragma unroll
    for (int j = 0; j < 16; ++j) woff += (j < wv) ? wsum[j] : 0;
    if (i < n) offs[i] = woff + sc - v;            // block-local exclusive
    if (t == 0) {
        int tot = 0;
        #pragma unroll
        for (int j = 0; j < 16; ++j) tot += wsum[j];
        bsum[blockIdx.x] = tot;
    }
}

__global__ __launch_bounds__(1024) void scanB_kernel(const int* __restrict__ bsum,
                                                     int* __restrict__ bbase, int nb) {
    __shared__ int wsum[16];
    int t = threadIdx.x, lane = t & 63, wv = t >> 6;
    int v = (t < nb) ? bsum[t] : 0;
    int sc = v;
    #pragma unroll
    for (int d = 1; d < 64; d <<= 1) {
        int u = __shfl_up(sc, d);
        if (lane >= d) sc += u;
    }
    if (lane == 63) wsum[wv] = sc;
    __syncthreads();
    int woff = 0;
    #pragma unroll
    for (int j = 0; j < 16; ++j) woff += (j < wv) ? wsum[j] : 0;
    if (t < nb) bbase[t] = woff + sc - v;
}

__global__ void scanC_kernel(int* __restrict__ offs, const int* __restrict__ bbase,
                             int n, int E) {
    int i = blockIdx.x * 256 + threadIdx.x;
    if (i < n) offs[i] = offs[i] + bbase[i >> 10];
    if (i == n) offs[n] = E;
}

// scatter edges into CSR slots; NO atomics (rank precomputed); 8 edges/thread
// packed entry: (src << 16) | fp16-bits(norm). REQUIRES n < 65536.
__global__ void fill_kernel(const int* __restrict__ row, const int* __restrict__ col,
                            const float* __restrict__ dinv, const int* __restrict__ offs,
                            const int* __restrict__ rank, unsigned* __restrict__ csr, int E) {
    int base = blockIdx.x * 2048 + threadIdx.x;
    #pragma unroll
    for (int j = 0; j < 8; ++j) {
        int e = base + j * 256;
        if (e < E) {
            int r = row[e], c = col[e];
            union { __half h; unsigned short u; } nh;
            nh.h = __float2half_rn(dinv[r] * dinv[c]);
            csr[offs[c] + rank[e]] = ((unsigned)r << 16) | (unsigned)nh.u;
        }
    }
}

// fp32 node-major -> fp16 node-major
__global__ __launch_bounds__(256) void convert_kernel(const float* __restrict__ x,
                                                      __half* __restrict__ xh, int n) {
    int g = blockIdx.x * 256 + threadIdx.x;
    if (g >= n * 32) return;
    float4 v = ((const float4*)x)[g];
    union { __half2 h; unsigned u; } a, b;
    a.h = __float22half2_rn(make_float2(v.x, v.y));
    b.h = __float22half2_rn(make_float2(v.z, v.w));
    ((uint2*)xh)[g] = make_uint2(a.u, b.u);
}

// conv weights: fp32 [l][k][n] -> fp16 [l][n][k]
__global__ void wtc_kernel(const float* __restrict__ W, _Float16* __restrict__ WT, int total) {
    int idx = blockIdx.x * 256 + threadIdx.x;
    if (idx >= total) return;
    int l = idx >> 14, rem = idx & 16383;
    int nrow = rem >> 7, kk = rem & 127;
    WT[idx] = (_Float16)W[(l << 14) + kk * C + nrow];
}

// dense weights: fp32 [k][256] -> fp16 [256][k]
__global__ void wdc_kernel(const float* __restrict__ wd, _Float16* __restrict__ WDT) {
    int idx = blockIdx.x * 256 + threadIdx.x;
    if (idx >= 256 * C) return;
    int nrow = idx >> 7, kk = idx & 127;
    WDT[idx] = (_Float16)wd[kk * 256 + nrow];
}

__device__ __forceinline__ void accum8(float* a, uint4 q, float w) {
    union { unsigned u; __half2 h; } c;
    float2 f;
    c.u = q.x; f = __half22float2(c.h); a[0] += w * f.x; a[1] += w * f.y;
    c.u = q.y; f = __half22float2(c.h); a[2] += w * f.x; a[3] += w * f.y;
    c.u = q.z; f = __half22float2(c.h); a[4] += w * f.x; a[5] += w * f.y;
    c.u = q.w; f = __half22float2(c.h); a[6] += w * f.x; a[7] += w * f.y;
}

__device__ __forceinline__ uint4 pack8(const float* a) {
    union { __half2 h; unsigned u; } c0, c1, c2, c3;
    c0.h = __float22half2_rn(make_float2(a[0], a[1]));
    c1.h = __float22half2_rn(make_float2(a[2], a[3]));
    c2.h = __float22half2_rn(make_float2(a[4], a[5]));
    c3.h = __float22half2_rn(make_float2(a[6], a[7]));
    return make_uint4(c0.u, c1.u, c2.u, c3.u);
}

__device__ __forceinline__ float norm_of(unsigned m) {
    union { unsigned short u; __half h; } nh;
    nh.u = (unsigned short)(m & 0xffffu);
    return __half2float(nh.h);
}

// ---------------- aggregation + residual ----------------
// half-wave (32 lanes) per node: 2 edge-slots x 16 chan-lanes (uint4 each);
// cascade unroll 8/4/1 per slot -> up to 16 gathers in flight per node, 32 per wave.
// z[i] = (1-a)(sum_j norm*x[j] + dinv^2*x[i]) + a*x0[i]
__global__ __launch_bounds__(256) void agg_kernel(
    const __half* __restrict__ xc, const __half* __restrict__ x0h,
    const int* __restrict__ offs, const unsigned* __restrict__ csr,
    const float* __restrict__ dinv, __half* __restrict__ z, int n)
{
    int node = blockIdx.x * 8 + (threadIdx.x >> 5);
    if (node >= n) return;
    int l32 = threadIdx.x & 31;
    int sub = l32 >> 4;          // edge slot 0..1
    int cg = l32 & 15;           // uint4 index within row
    const uint4* x4 = (const uint4*)xc;
    float a0[8] = {}, a1[8] = {}, a2[8] = {}, a3[8] = {};
    int beg = offs[node], end = offs[node + 1];
    int k = beg + sub;
    for (; k + 14 < end; k += 16) {          // 8 edges per slot in flight
        unsigned m0 = csr[k], m1 = csr[k + 2], m2 = csr[k + 4], m3 = csr[k + 6];
        unsigned m4 = csr[k + 8], m5 = csr[k + 10], m6 = csr[k + 12], m7 = csr[k + 14];
        uint4 q0 = x4[(size_t)(m0 >> 16) * 16 + cg];
        uint4 q1 = x4[(size_t)(m1 >> 16) * 16 + cg];
        uint4 q2 = x4[(size_t)(m2 >> 16) * 16 + cg];
        uint4 q3 = x4[(size_t)(m3 >> 16) * 16 + cg];
        uint4 q4 = x4[(size_t)(m4 >> 16) * 16 + cg];
        uint4 q5 = x4[(size_t)(m5 >> 16) * 16 + cg];
        uint4 q6 = x4[(size_t)(m6 >> 16) * 16 + cg];
        uint4 q7 = x4[(size_t)(m7 >> 16) * 16 + cg];
        accum8(a0, q0, norm_of(m0));
        accum8(a1, q1, norm_of(m1));
        accum8(a2, q2, norm_of(m2));
        accum8(a3, q3, norm_of(m3));
        accum8(a0, q4, norm_of(m4));
        accum8(a1, q5, norm_of(m5));
        accum8(a2, q6, norm_of(m6));
        accum8(a3, q7, norm_of(m7));
    }
    for (; k + 6 < end; k += 8) {            // 4 edges per slot in flight
        unsigned m0 = csr[k], m1 = csr[k + 2], m2 = csr[k + 4], m3 = csr[k + 6];
        uint4 q0 = x4[(size_t)(m0 >> 16) * 16 + cg];
        uint4 q1 = x4[(size_t)(m1 >> 16) * 16 + cg];
        uint4 q2 = x4[(size_t)(m2 >> 16) * 16 + cg];
        uint4 q3 = x4[(size_t)(m3 >> 16) * 16 + cg];
        accum8(a0, q0, norm_of(m0));
        accum8(a1, q1, norm_of(m1));
        accum8(a2, q2, norm_of(m2));
        accum8(a3, q3, norm_of(m3));
    }
    for (; k < end; k += 2) {
        unsigned m = csr[k];
        uint4 q = x4[(size_t)(m >> 16) * 16 + cg];
        accum8(a0, q, norm_of(m));
    }
    #pragma unroll
    for (int j = 0; j < 8; ++j) a0[j] += a1[j] + a2[j] + a3[j];
    #pragma unroll
    for (int j = 0; j < 8; ++j) a0[j] += __shfl_xor(a0[j], 16);
    if (sub == 0) {
        float di = dinv[node], sw = di * di;
        uint4 qs = x4[(size_t)node * 16 + cg];
        accum8(a0, qs, sw);
        uint4 q0x = ((const uint4*)x0h)[(size_t)node * 16 + cg];
        float xr[8] = {};
        accum8(xr, q0x, 1.f);
        float zz[8];
        #pragma unroll
        for (int j = 0; j < 8; ++j) zz[j] = (1.f - ALPHA) * a0[j] + ALPHA * xr[j];
        ((uint4*)z)[(size_t)node * 16 + cg] = pack8(zz);
    }
}

// ---------------- layer GEMM (MFMA, B-in-registers): xn = leaky(z @ W)
// 64 nodes/block, 4 waves; wave w owns cols [32w,32w+32) (2 n-tiles), all 64 rows.
__global__ __launch_bounds__(256) void layer_mfma(
    const __half* __restrict__ zin, const _Float16* __restrict__ WT,
    __half* __restrict__ xn, int n)
{
    __shared__ _Float16 zl[64 * ZP];
    __shared__ _Float16 ol[64 * ZP];
    int i0 = blockIdx.x * 64;
    int t = threadIdx.x;
    int w = t >> 6, lane = t & 63;
    int c = lane & 15, g = lane >> 4;

    const uint4* z4 = (const uint4*)zin;
    for (int p = t; p < 64 * 16; p += 256) {
        int r = p >> 4, c8 = p & 15;
        uint4 zv = make_uint4(0, 0, 0, 0);
        if (i0 + r < n) zv = z4[(size_t)(i0 + r) * 16 + c8];
        *(uint4*)&zl[r * ZP + c8 * 8] = zv;
    }

    // hoist B fragments for this wave's 2 n-tiles
    half4v bf[8][2];
    #pragma unroll
    for (int kb = 0; kb < 8; ++kb)
        #pragma unroll
        for (int nt = 0; nt < 2; ++nt)
            bf[kb][nt] = *(const half4v*)&WT[((w * 2 + nt) * 16 + c) * C + kb * 16 + 4 * g];

    __syncthreads();

    #pragma unroll
    for (int m = 0; m < 4; ++m) {
        const _Float16* arow = &zl[(m * 16 + c) * ZP];
        half4v af[8];
        #pragma unroll
        for (int kb = 0; kb < 8; ++kb) af[kb] = *(const half4v*)&arow[kb * 16 + 4 * g];
        float4v acc0 = (float4v)0.f, acc1 = (float4v)0.f;
        #pragma unroll
        for (int kb = 0; kb < 8; ++kb) {
            acc0 = __builtin_amdgcn_mfma_f32_16x16x16f16(af[kb], bf[kb][0], acc0, 0, 0, 0);
            acc1 = __builtin_amdgcn_mfma_f32_16x16x16f16(af[kb], bf[kb][1], acc1, 0, 0, 0);
        }
        #pragma unroll
        for (int r = 0; r < 4; ++r) {
            float v0 = acc0[r]; v0 = v0 > 0.f ? v0 : SLOPE * v0;
            float v1 = acc1[r]; v1 = v1 > 0.f ? v1 : SLOPE * v1;
            ol[(m * 16 + 4 * g + r) * ZP + (w * 2 + 0) * 16 + c] = (_Float16)v0;
            ol[(m * 16 + 4 * g + r) * ZP + (w * 2 + 1) * 16 + c] = (_Float16)v1;
        }
    }
    __syncthreads();
    for (int p = t; p < 64 * 16; p += 256) {
        int r = p >> 4, c8 = p & 15;
        int node = i0 + r;
        if (node < n)
            ((uint4*)xn)[(size_t)node * 16 + c8] = *(uint4*)&ol[r * ZP + c8 * 8];
    }
}

// ---------------- dense head (MFMA, B-in-registers): out = (x@wd + bd) @ wo + bo
__global__ __launch_bounds__(256) void dense_mfma(
    const __half* __restrict__ xin, const _Float16* __restrict__ WDT,
    const float* __restrict__ bd, const float* __restrict__ wo,
    const float* __restrict__ bo, float* __restrict__ out, int n)
{
    __shared__ _Float16 xl[64 * ZP];
    __shared__ float pp[64][4][2];
    int i0 = blockIdx.x * 64;
    int t = threadIdx.x;
    int w = t >> 6, lane = t & 63;
    int c = lane & 15, g = lane >> 4;

    const uint4* g4 = (const uint4*)xin;
    for (int p = t; p < 64 * 16; p += 256) {
        int r = p >> 4, c8 = p & 15;
        uint4 v = make_uint4(0, 0, 0, 0);
        if (i0 + r < n) v = g4[(size_t)(i0 + r) * 16 + c8];
        *(uint4*)&xl[r * ZP + c8 * 8] = v;
    }

    half4v bf[8][4];
    #pragma unroll
    for (int kb = 0; kb < 8; ++kb)
        #pragma unroll
        for (int nt = 0; nt < 4; ++nt)
            bf[kb][nt] = *(const half4v*)&WDT[((w * 4 + nt) * 16 + c) * C + kb * 16 + 4 * g];
    float bdv[4], wo0[4], wo1[4];
    #pragma unroll
    for (int nt = 0; nt < 4; ++nt) {
        int coln = (w * 4 + nt) * 16 + c;
        bdv[nt] = bd[coln];
        wo0[nt] = wo[coln * 2 + 0];
        wo1[nt] = wo[coln * 2 + 1];
    }

    __syncthreads();

    #pragma unroll
    for (int m = 0; m < 4; ++m) {
        const _Float16* arow = &xl[(m * 16 + c) * ZP];
        half4v af[8];
        #pragma unroll
        for (int kb = 0; kb < 8; ++kb) af[kb] = *(const half4v*)&arow[kb * 16 + 4 * g];
        float4v acc[4];
        #pragma unroll
        for (int nt = 0; nt < 4; ++nt) acc[nt] = (float4v)0.f;
        #pragma unroll
        for (int kb = 0; kb < 8; ++kb) {
            #pragma unroll
            for (int nt = 0; nt < 4; ++nt)
                acc[nt] = __builtin_amdgcn_mfma_f32_16x16x16f16(af[kb], bf[kb][nt], acc[nt], 0, 0, 0);
        }
        float p0[4] = {0.f, 0.f, 0.f, 0.f}, p1[4] = {0.f, 0.f, 0.f, 0.f};
        #pragma unroll
        for (int nt = 0; nt < 4; ++nt) {
            #pragma unroll
            for (int r = 0; r < 4; ++r) {
                float hv = acc[nt][r] + bdv[nt];
                p0[r] += hv * wo0[nt];
                p1[r] += hv * wo1[nt];
            }
        }
        #pragma unroll
        for (int ms = 1; ms <= 8; ms <<= 1) {
            #pragma unroll
            for (int r = 0; r < 4; ++r) {
                p0[r] += __shfl_xor(p0[r], ms);
                p1[r] += __shfl_xor(p1[r], ms);
            }
        }
        if (c == 0) {
            #pragma unroll
            for (int r = 0; r < 4; ++r) {
                pp[m * 16 + 4 * g + r][w][0] = p0[r];
                pp[m * 16 + 4 * g + r][w][1] = p1[r];
            }
        }
    }
    __syncthreads();
    if (t < 128) {
        int r = t >> 1, o = t & 1;
        int node = i0 + r;
        if (node < n) {
            float s = pp[r][0][o] + pp[r][1][o] + pp[r][2][o] + pp[r][3][o];
            out[(size_t)node * NOUT + o] = s + bo[o];
        }
    }
}

extern "C" void kernel_launch(void* const* d_in, const int* in_sizes, int n_in,
                              void* d_out, int out_size, void* d_ws, size_t ws_size,
                              hipStream_t stream) {
    const float* x0    = (const float*)d_in[0];
    const int*   ei    = (const int*)d_in[1];
    const float* convW = (const float*)d_in[2];
    const float* wd    = (const float*)d_in[3];
    const float* bd    = (const float*)d_in[4];
    const float* wo    = (const float*)d_in[5];
    const float* bo    = (const float*)d_in[6];
    float* out = (float*)d_out;

    int N = in_sizes[0] / C;
    int E = in_sizes[1] / 2;
    int L = in_sizes[2] / (C * C);
    const int* row = ei;
    const int* col = ei + E;
    int NB = (N + 1023) / 1024;

    char* p = (char*)d_ws;
    auto alloc = [&](size_t bytes) {
        char* r = p;
        p += (bytes + 255) & ~(size_t)255;
        return r;
    };
    int*      cnt    = (int*)alloc((size_t)N * 4);
    int*      offs   = (int*)alloc((size_t)(N + 1) * 4);
    int*      rank   = (int*)alloc((size_t)E * 4);
    int*      bsum   = (int*)alloc((size_t)NB * 4);
    int*      bbase  = (int*)alloc((size_t)NB * 4);
    unsigned* csr    = (unsigned*)alloc((size_t)E * 4);
    float*    dinv   = (float*)alloc((size_t)N * 4);
    __half*   x0h    = (__half*)alloc((size_t)N * C * 2);
    __half*   bufA   = (__half*)alloc((size_t)N * C * 2);
    __half*   zbuf   = (__half*)alloc((size_t)N * C * 2);
    _Float16* WT     = (_Float16*)alloc((size_t)L * C * C * 2);
    _Float16* WDT    = (_Float16*)alloc((size_t)256 * C * 2);

    hipMemsetAsync(cnt, 0, (size_t)N * 4, stream);
    count_kernel<<<(E + 255) / 256, 256, 0, stream>>>(col, cnt, rank, E);
    scanA_kernel<<<NB, 1024, 0, stream>>>(cnt, offs, bsum, dinv, N);
    scanB_kernel<<<1, 1024, 0, stream>>>(bsum, bbase, NB);
    scanC_kernel<<<(N + 256) / 256, 256, 0, stream>>>(offs, bbase, N, E);
    fill_kernel<<<(E + 2047) / 2048, 256, 0, stream>>>(row, col, dinv, offs, rank, csr, E);
    convert_kernel<<<(N * 32 + 255) / 256, 256, 0, stream>>>(x0, x0h, N);
    int wtot = L * C * C;
    wtc_kernel<<<(wtot + 255) / 256, 256, 0, stream>>>(convW, WT, wtot);
    wdc_kernel<<<(256 * C + 255) / 256, 256, 0, stream>>>(wd, WDT);

    const __half* xc = x0h;
    for (int l = 0; l < L; ++l) {
        agg_kernel<<<(N + 7) / 8, 256, 0, stream>>>(xc, x0h, offs, csr, dinv, zbuf, N);
        layer_mfma<<<(N + 63) / 64, 256, 0, stream>>>(zbuf, WT + (size_t)l * C * C,
                                                      bufA, N);
        xc = bufA;
    }
    dense_mfma<<<(N + 63) / 64, 256, 0, stream>>>(xc, WDT, bd, wo, bo, out, N);
}